// Round 2
// baseline (420.288 us; speedup 1.0000x reference)
//
#include <hip/hip_runtime.h>

// x [4,64,256,256] f32, flow [4,2,256,256] f32 -> out [4,320,256,256] f32
#define BB 4
#define CC 64
#define HH 256
#define WW 256
#define HWHW (HH * WW)

// Kernel A: transpose x [B,C,HW] -> xt [B,HW,C] so gather taps are coalesced.
// float4 on both global phases (1 KB/wave-instr); LDS stays scalar with the
// 65-pad (65 % 32 == 1 -> bank ~ c+px, <=2-way on both phases, free).
__global__ __launch_bounds__(256) void transpose_xk(const float* __restrict__ x,
                                                    float* __restrict__ xt) {
    __shared__ float tile[64][65];
    const int b = blockIdx.y;
    const int hw0 = blockIdx.x << 6;
    const int t = threadIdx.x;
    const float* xb = x + (size_t)b * CC * HWHW;

    const int cq = t >> 4;          // 0..15
    const int px4 = (t & 15) << 2;  // 0,4,...,60
#pragma unroll
    for (int k = 0; k < 4; ++k) {
        const int c = cq + (k << 4);
        const float4 v = *(const float4*)&xb[(size_t)c * HWHW + hw0 + px4];
        tile[c][px4 + 0] = v.x;
        tile[c][px4 + 1] = v.y;
        tile[c][px4 + 2] = v.z;
        tile[c][px4 + 3] = v.w;
    }
    __syncthreads();
    float* xtb = xt + ((size_t)b * HWHW << 6);
    const int hwq = t >> 4;         // 0..15
    const int c4 = (t & 15) << 2;   // 0,4,...,60
#pragma unroll
    for (int k = 0; k < 4; ++k) {
        const int hw = hwq + (k << 4);
        float4 v;
        v.x = tile[c4 + 0][hw];
        v.y = tile[c4 + 1][hw];
        v.z = tile[c4 + 2][hw];
        v.w = tile[c4 + 3][hw];
        *(float4*)&xtb[((size_t)(hw0 + hw) << 6) + c4] = v;
    }
}

// Kernel B: fused 5-variant OBMC warp.
// XCD-aware swizzle (round 1) + NEW software pipeline: gathers for g+1 are
// issued before the FMA/store phase of g, so L2/L3 gather latency hides
// under compute + barrier + coalesced stores. sm is double-buffered by g
// parity, which removes the second barrier per g (5+1 barriers vs 10+1).
__global__ __launch_bounds__(256) void obmc_kernel(const float* __restrict__ xt,
                                                   const float* __restrict__ flow,
                                                   float* __restrict__ out) {
    __shared__ int4 dOff[5][64];      // clamped tap offsets (element idx, <<6)
    __shared__ float4 dW[5][64];      // validity-masked bilinear weights
    __shared__ float sm[2][64][65];   // double-buffered [c][px] store staging

    // bijective XCD swizzle (4096 % 8 == 0): each XCD owns a contiguous
    // half-image -> in-flight gather window fits the 4 MB per-XCD L2.
    const int bid = ((blockIdx.x & 7) << 9) + (blockIdx.x >> 3);
    const int tx0 = (bid & 3) << 6;
    const int y = (bid >> 2) & 255;
    const int b = bid >> 10;
    const int t = threadIdx.x;
    const int wv = t >> 6;
    const int lane = t & 63;
    const int sp = lane >> 4;
    const int c4 = (lane & 15) << 2;

    const float* xtb = xt + ((size_t)b * HWHW << 6);
    const float* fb = flow + (size_t)b * 2 * HWHW;
    float* ob = out + (size_t)b * 5 * CC * HWHW + (size_t)y * WW + tx0;

    const int oys[5] = {0, 1, 0, -1, 0};
    const int oxs[5] = {0, 0, 1, 0, -1};

    // ---- pre-phase: 320 descriptors by 256 threads ----
    for (int idx = t; idx < 320; idx += 256) {
        const int g = idx >> 6, px = idx & 63;
        const int sy = y + oys[g];
        const int sx = tx0 + px + oxs[g];
        float fx = 0.f, fy = 0.f;
        if ((unsigned)sy < HH && (unsigned)sx < WW) {
            const int fo = sy * WW + sx;
            fx = fb[fo];
            fy = fb[HWHW + fo];
        }
        const float gx = (float)(tx0 + px) + fx;
        const float gy = (float)y + fy;
        const float x0f = floorf(gx);
        const float y0f = floorf(gy);
        const float fwx = gx - x0f;
        const float fwy = gy - y0f;
        const int ix0 = (int)x0f, iy0 = (int)y0f;
        const int ix1 = ix0 + 1, iy1 = iy0 + 1;
        const float vx0 = ((unsigned)ix0 < WW) ? 1.f : 0.f;
        const float vx1 = ((unsigned)ix1 < WW) ? 1.f : 0.f;
        const float vy0 = ((unsigned)iy0 < HH) ? 1.f : 0.f;
        const float vy1 = ((unsigned)iy1 < HH) ? 1.f : 0.f;
        const int xc0 = min(max(ix0, 0), WW - 1);
        const int xc1 = min(max(ix1, 0), WW - 1);
        const int yc0 = min(max(iy0, 0), HH - 1);
        const int yc1 = min(max(iy1, 0), HH - 1);
        dOff[g][px] = make_int4((yc0 * WW + xc0) << 6, (yc0 * WW + xc1) << 6,
                                (yc1 * WW + xc0) << 6, (yc1 * WW + xc1) << 6);
        dW[g][px] = make_float4((1.f - fwx) * (1.f - fwy) * vx0 * vy0,
                                fwx * (1.f - fwy) * vx1 * vy0,
                                (1.f - fwx) * fwy * vx0 * vy1,
                                fwx * fwy * vx1 * vy1);
    }
    __syncthreads();

    float4 va[16], vb[16];

    // Issue all 16 gathers for variant G into bank DST (compile-time G).
#define LOADG(G, DST)                                                          \
    {                                                                          \
        _Pragma("unroll") for (int i = 0; i < 4; ++i) {                        \
            const int px = (wv << 4) + (i << 2) + sp;                          \
            const int4 o = dOff[G][px]; /* broadcast ds_read_b128 */           \
            DST[(i << 2) + 0] = *(const float4*)(xtb + o.x + c4);              \
            DST[(i << 2) + 1] = *(const float4*)(xtb + o.y + c4);              \
            DST[(i << 2) + 2] = *(const float4*)(xtb + o.z + c4);              \
            DST[(i << 2) + 3] = *(const float4*)(xtb + o.w + c4);              \
        }                                                                      \
    }

    // One pipelined variant step: prefetch G+1 into NXT, then FMA from CUR,
    // LDS bounce into sm[G&1], single barrier, coalesced nontemporal stores.
#define GBODY(G, CUR, NXT, DO_NEXT)                                            \
    {                                                                          \
        if (DO_NEXT) LOADG((G) + 1, NXT);                                      \
        _Pragma("unroll") for (int i = 0; i < 4; ++i) {                        \
            const int px = (wv << 4) + (i << 2) + sp;                          \
            const float4 w = dW[G][px]; /* broadcast ds_read_b128 */           \
            float4 a;                                                          \
            a.x = w.x * CUR[(i << 2)].x;                                       \
            a.y = w.x * CUR[(i << 2)].y;                                       \
            a.z = w.x * CUR[(i << 2)].z;                                       \
            a.w = w.x * CUR[(i << 2)].w;                                       \
            a.x = fmaf(w.y, CUR[(i << 2) + 1].x, a.x);                         \
            a.y = fmaf(w.y, CUR[(i << 2) + 1].y, a.y);                         \
            a.z = fmaf(w.y, CUR[(i << 2) + 1].z, a.z);                         \
            a.w = fmaf(w.y, CUR[(i << 2) + 1].w, a.w);                         \
            a.x = fmaf(w.z, CUR[(i << 2) + 2].x, a.x);                         \
            a.y = fmaf(w.z, CUR[(i << 2) + 2].y, a.y);                         \
            a.z = fmaf(w.z, CUR[(i << 2) + 2].z, a.z);                         \
            a.w = fmaf(w.z, CUR[(i << 2) + 2].w, a.w);                         \
            a.x = fmaf(w.w, CUR[(i << 2) + 3].x, a.x);                         \
            a.y = fmaf(w.w, CUR[(i << 2) + 3].y, a.y);                         \
            a.z = fmaf(w.w, CUR[(i << 2) + 3].z, a.z);                         \
            a.w = fmaf(w.w, CUR[(i << 2) + 3].w, a.w);                         \
            sm[(G) & 1][c4 + 0][px] = a.x;                                     \
            sm[(G) & 1][c4 + 1][px] = a.y;                                     \
            sm[(G) & 1][c4 + 2][px] = a.z;                                     \
            sm[(G) & 1][c4 + 3][px] = a.w;                                     \
        }                                                                      \
        __syncthreads();                                                       \
        _Pragma("unroll") for (int k = 0; k < 16; ++k) {                       \
            const int c = (wv << 4) + k;                                       \
            __builtin_nontemporal_store(                                       \
                sm[(G) & 1][c][lane],                                          \
                &ob[(size_t)((G)*CC + c) * HWHW + lane]);                      \
        }                                                                      \
    }

    LOADG(0, va);
    GBODY(0, va, vb, 1);
    GBODY(1, vb, va, 1);
    GBODY(2, va, vb, 1);
    GBODY(3, vb, va, 1);
    GBODY(4, va, vb, 0);
#undef GBODY
#undef LOADG
}

extern "C" void kernel_launch(void* const* d_in, const int* in_sizes, int n_in,
                              void* d_out, int out_size, void* d_ws, size_t ws_size,
                              hipStream_t stream) {
    const float* x = (const float*)d_in[0];
    const float* flow = (const float*)d_in[1];
    float* out = (float*)d_out;
    float* xt = (float*)d_ws;  // 64 MiB scratch

    transpose_xk<<<dim3(HWHW / 64, BB), 256, 0, stream>>>(x, xt);
    obmc_kernel<<<BB * HH * (WW / 64), 256, 0, stream>>>(xt, flow, out);
}

// Round 4
// 394.162 us; speedup vs baseline: 1.0663x; 1.0663x over previous
//
#include <hip/hip_runtime.h>
#include <hip/hip_fp16.h>

// x [4,64,256,256] f32, flow [4,2,256,256] f32 -> out [4,320,256,256] f32
#define BB 4
#define CC 64
#define HH 256
#define WW 256
#define HWHW (HH * WW)

typedef float vf4 __attribute__((ext_vector_type(4)));  // NT-load-able float4

union H4 {
    __half2 h2[2];
    uint2 u;
};

// Load 4 fp16 channels (8 B) and widen to f32.
__device__ __forceinline__ float4 ld4h(const __half* p) {
    const H4 r = *(const H4*)p;
    const float2 a = __half22float2(r.h2[0]);
    const float2 b = __half22float2(r.h2[1]);
    return make_float4(a.x, a.y, b.x, b.y);
}

// Kernel A: transpose+downconvert x [B,C,HW] f32 -> xt [B,HW,C] fp16 so
// gather taps are coalesced AND half-width (one 128B line per tap).
// NT loads on x (never re-read -> keep L2/L3 clean for xt).
__global__ __launch_bounds__(256) void transpose_xk(const float* __restrict__ x,
                                                    __half* __restrict__ xt) {
    __shared__ float tile[64][65];
    const int b = blockIdx.y;
    const int hw0 = blockIdx.x << 6;
    const int t = threadIdx.x;
    const float* xb = x + (size_t)b * CC * HWHW;

    const int cq = t >> 4;          // 0..15
    const int px4 = (t & 15) << 2;  // 0,4,...,60
#pragma unroll
    for (int k = 0; k < 4; ++k) {
        const int c = cq + (k << 4);
        const vf4 v = __builtin_nontemporal_load(
            (const vf4*)&xb[(size_t)c * HWHW + hw0 + px4]);
        tile[c][px4 + 0] = v.x;
        tile[c][px4 + 1] = v.y;
        tile[c][px4 + 2] = v.z;
        tile[c][px4 + 3] = v.w;
    }
    __syncthreads();
    __half* xtb = xt + ((size_t)b * HWHW << 6);
    const int hwq = t >> 4;         // 0..15
    const int c4 = (t & 15) << 2;   // 0,4,...,60
#pragma unroll
    for (int k = 0; k < 4; ++k) {
        const int hw = hwq + (k << 4);
        H4 h;
        h.h2[0] = __floats2half2_rn(tile[c4 + 0][hw], tile[c4 + 1][hw]);
        h.h2[1] = __floats2half2_rn(tile[c4 + 2][hw], tile[c4 + 3][hw]);
        *(uint2*)&xtb[((size_t)(hw0 + hw) << 6) + c4] = h.u;  // 128B/16 lanes
    }
}

// Kernel B: fused 5-variant OBMC warp (round-1 structure: 2 barriers/g,
// single sm buffer, no reg pipeline -- occupancy is the latency hider).
// XCD-aware swizzle keeps each XCD's tap window in its own L2; with fp16
// xt the window is ~2.6 MB and fits the 4 MB per-XCD L2.
__global__ __launch_bounds__(256) void obmc_kernel(const __half* __restrict__ xt,
                                                   const float* __restrict__ flow,
                                                   float* __restrict__ out) {
    __shared__ int4 dOff[5][64];    // clamped tap offsets (half-element idx, <<6)
    __shared__ float4 dW[5][64];    // validity-masked bilinear weights
    __shared__ float sm[64][65];    // [c][px] staging for coalesced stores

    // bijective XCD swizzle (4096 % 8 == 0)
    const int bid = ((blockIdx.x & 7) << 9) + (blockIdx.x >> 3);
    const int tx0 = (bid & 3) << 6;
    const int y = (bid >> 2) & 255;
    const int b = bid >> 10;
    const int t = threadIdx.x;
    const int wv = t >> 6;
    const int lane = t & 63;
    const int sp = lane >> 4;
    const int c4 = (lane & 15) << 2;

    const __half* xtb = xt + ((size_t)b * HWHW << 6);
    const float* fb = flow + (size_t)b * 2 * HWHW;
    float* ob = out + (size_t)b * 5 * CC * HWHW + (size_t)y * WW + tx0;

    const int oys[5] = {0, 1, 0, -1, 0};
    const int oxs[5] = {0, 0, 1, 0, -1};

    // ---- pre-phase: 320 descriptors by 256 threads ----
    for (int idx = t; idx < 320; idx += 256) {
        const int g = idx >> 6, px = idx & 63;
        const int sy = y + oys[g];
        const int sx = tx0 + px + oxs[g];
        float fx = 0.f, fy = 0.f;
        if ((unsigned)sy < HH && (unsigned)sx < WW) {
            const int fo = sy * WW + sx;
            fx = fb[fo];
            fy = fb[HWHW + fo];
        }
        const float gx = (float)(tx0 + px) + fx;
        const float gy = (float)y + fy;
        const float x0f = floorf(gx);
        const float y0f = floorf(gy);
        const float fwx = gx - x0f;
        const float fwy = gy - y0f;
        const int ix0 = (int)x0f, iy0 = (int)y0f;
        const int ix1 = ix0 + 1, iy1 = iy0 + 1;
        const float vx0 = ((unsigned)ix0 < WW) ? 1.f : 0.f;
        const float vx1 = ((unsigned)ix1 < WW) ? 1.f : 0.f;
        const float vy0 = ((unsigned)iy0 < HH) ? 1.f : 0.f;
        const float vy1 = ((unsigned)iy1 < HH) ? 1.f : 0.f;
        const int xc0 = min(max(ix0, 0), WW - 1);
        const int xc1 = min(max(ix1, 0), WW - 1);
        const int yc0 = min(max(iy0, 0), HH - 1);
        const int yc1 = min(max(iy1, 0), HH - 1);
        dOff[g][px] = make_int4((yc0 * WW + xc0) << 6, (yc0 * WW + xc1) << 6,
                                (yc1 * WW + xc0) << 6, (yc1 * WW + xc1) << 6);
        dW[g][px] = make_float4((1.f - fwx) * (1.f - fwy) * vx0 * vy0,
                                fwx * (1.f - fwy) * vx1 * vy0,
                                (1.f - fwx) * fwy * vx0 * vy1,
                                fwx * fwy * vx1 * vy1);
    }
    __syncthreads();

    for (int g = 0; g < 5; ++g) {
        float4 acc[4];
#pragma unroll
        for (int i = 0; i < 4; ++i) {
            const int px = (wv << 4) + (i << 2) + sp;
            const int4 o = dOff[g][px];     // broadcast ds_read_b128
            const float4 w = dW[g][px];     // broadcast ds_read_b128
            const float4 v0 = ld4h(xtb + o.x + c4);
            const float4 v1 = ld4h(xtb + o.y + c4);
            const float4 v2 = ld4h(xtb + o.z + c4);
            const float4 v3 = ld4h(xtb + o.w + c4);
            float4 a;
            a.x = w.x * v0.x; a.y = w.x * v0.y; a.z = w.x * v0.z; a.w = w.x * v0.w;
            a.x = fmaf(w.y, v1.x, a.x); a.y = fmaf(w.y, v1.y, a.y);
            a.z = fmaf(w.y, v1.z, a.z); a.w = fmaf(w.y, v1.w, a.w);
            a.x = fmaf(w.z, v2.x, a.x); a.y = fmaf(w.z, v2.y, a.y);
            a.z = fmaf(w.z, v2.z, a.z); a.w = fmaf(w.z, v2.w, a.w);
            a.x = fmaf(w.w, v3.x, a.x); a.y = fmaf(w.w, v3.y, a.y);
            a.z = fmaf(w.w, v3.z, a.z); a.w = fmaf(w.w, v3.w, a.w);
            acc[i] = a;
        }
#pragma unroll
        for (int i = 0; i < 4; ++i) {
            const int px = (wv << 4) + (i << 2) + sp;
            sm[c4 + 0][px] = acc[i].x;
            sm[c4 + 1][px] = acc[i].y;
            sm[c4 + 2][px] = acc[i].z;
            sm[c4 + 3][px] = acc[i].w;
        }
        __syncthreads();
#pragma unroll
        for (int k = 0; k < 16; ++k) {
            const int c = (wv << 4) + k;
            __builtin_nontemporal_store(sm[c][lane],
                                        &ob[(size_t)(g * CC + c) * HWHW + lane]);
        }
        __syncthreads();
    }
}

extern "C" void kernel_launch(void* const* d_in, const int* in_sizes, int n_in,
                              void* d_out, int out_size, void* d_ws, size_t ws_size,
                              hipStream_t stream) {
    const float* x = (const float*)d_in[0];
    const float* flow = (const float*)d_in[1];
    float* out = (float*)d_out;
    __half* xt = (__half*)d_ws;  // 32 MiB scratch (fp16)

    transpose_xk<<<dim3(HWHW / 64, BB), 256, 0, stream>>>(x, xt);
    obmc_kernel<<<BB * HH * (WW / 64), 256, 0, stream>>>(xt, flow, out);
}